// Round 7
// baseline (633.890 us; speedup 1.0000x reference)
//
#include <hip/hip_runtime.h>
#include <hip/hip_bf16.h>
#include <hip/hip_cooperative_groups.h>

namespace cg = cooperative_groups;

#define N_NODES 50000
#define N_EDGES 800000
#define DIN 256
#define DHID 128
#define DOUT 128
#define NBLK 196      // ceil(N_NODES/256)
#define CSR_GRID 784  // blocks for the cooperative CSR kernel (>= NBLK)

typedef __attribute__((ext_vector_type(8))) short bf16x8;
typedef __attribute__((ext_vector_type(4))) float f32x4;

__device__ inline unsigned short f2b(float f) {
    __hip_bfloat16 b = __float2bfloat16(f);
    return *reinterpret_cast<unsigned short*>(&b);
}

// ---------------- transpose+cast both weights in one dispatch
__global__ __launch_bounds__(256) void convW_kernel(
    const float* __restrict__ W1, const float* __restrict__ W2,
    unsigned short* __restrict__ W1t, unsigned short* __restrict__ W2t)
{
    int i = blockIdx.x * 256 + threadIdx.x;
    if (i < DIN * DHID) {
        int n = i >> 8, k = i & 255;
        W1t[i] = f2b(W1[k * DHID + n]);
    } else {
        int j = i - DIN * DHID;
        int n = j >> 7, k = j & 127;
        W2t[j] = f2b(W2[k * DOUT + n]);
    }
}

// ---------------- gemm1: hb = bf16( bf16(x) @ W1t^T ), MFMA 16x16x32.
// W1t staged in 64KB LDS; x read f32 + converted in-register.
// Fused epilogue: es = h.att_src, ed = h.att_dst.
__global__ __launch_bounds__(256) void gemm1_mfma(
    const float* __restrict__ x,
    const unsigned short* __restrict__ W1t,
    const float* __restrict__ att_src,
    const float* __restrict__ att_dst,
    unsigned short* __restrict__ hb,
    float* __restrict__ es,
    float* __restrict__ ed)
{
    __shared__ unsigned short W1s[DHID * DIN];   // 64 KB

    const int tid = threadIdx.x;
    const int wave = tid >> 6, lane = tid & 63;
    const int row0 = blockIdx.x * 64 + wave * 16;
    const int m = lane & 15, q = lane >> 4;

    {
        const float4* src = (const float4*)W1t;
        float4* dst = (float4*)W1s;
        #pragma unroll
        for (int i = 0; i < 16; ++i)
            dst[tid + i * 256] = src[tid + i * 256];
    }
    __syncthreads();

    int r  = row0 + m;
    int rc = (r < N_NODES) ? r : 0;

    f32x4 acc[8];
    #pragma unroll
    for (int t = 0; t < 8; ++t) acc[t] = (f32x4){0.f, 0.f, 0.f, 0.f};

    const float* xr = x + (size_t)rc * DIN + q * 8;
    const short* wp = (const short*)W1s + q * 8;

    #pragma unroll
    for (int kt = 0; kt < 8; ++kt) {
        float4 f0 = *(const float4*)(xr + kt * 32);
        float4 f1 = *(const float4*)(xr + kt * 32 + 4);
        bf16x8 a;
        a[0] = (short)f2b(f0.x); a[1] = (short)f2b(f0.y);
        a[2] = (short)f2b(f0.z); a[3] = (short)f2b(f0.w);
        a[4] = (short)f2b(f1.x); a[5] = (short)f2b(f1.y);
        a[6] = (short)f2b(f1.z); a[7] = (short)f2b(f1.w);
        #pragma unroll
        for (int t = 0; t < 8; ++t) {
            bf16x8 b = *(const bf16x8*)(wp + (t * 16 + m) * DIN + kt * 32);
            acc[t] = __builtin_amdgcn_mfma_f32_16x16x32_bf16(a, b, acc[t], 0, 0, 0);
        }
    }

    #pragma unroll
    for (int reg = 0; reg < 4; ++reg) {
        int rr = row0 + q * 4 + reg;
        if (rr < N_NODES) {
            #pragma unroll
            for (int t = 0; t < 8; ++t)
                hb[(size_t)rr * DHID + t * 16 + m] = f2b(acc[t][reg]);
        }
    }

    float esr[4] = {0.f, 0.f, 0.f, 0.f}, edr[4] = {0.f, 0.f, 0.f, 0.f};
    #pragma unroll
    for (int t = 0; t < 8; ++t) {
        float as = att_src[t * 16 + m];
        float ad = att_dst[t * 16 + m];
        #pragma unroll
        for (int reg = 0; reg < 4; ++reg) {
            esr[reg] += acc[t][reg] * as;
            edr[reg] += acc[t][reg] * ad;
        }
    }
    #pragma unroll
    for (int off = 8; off; off >>= 1)
        #pragma unroll
        for (int reg = 0; reg < 4; ++reg) {
            esr[reg] += __shfl_xor(esr[reg], off);
            edr[reg] += __shfl_xor(edr[reg], off);
        }
    if (m == 0) {
        #pragma unroll
        for (int reg = 0; reg < 4; ++reg) {
            int rr = row0 + q * 4 + reg;
            if (rr < N_NODES) { es[rr] = esr[reg]; ed[rr] = edr[reg]; }
        }
    }
}

// ---------------- cooperative CSR build: zero + hist + 2-level scan + weighted scatter
__global__ __launch_bounds__(256) void csr_kernel(
    const int* __restrict__ ei,
    const float* __restrict__ es,
    const float* __restrict__ ed,
    int* __restrict__ count,
    int* __restrict__ offset,
    int* __restrict__ blockSums,
    int* __restrict__ blockOffsets,
    int2* __restrict__ sortedSW)
{
    cg::grid_group grid = cg::this_grid();
    const int t   = threadIdx.x;
    const int gid = blockIdx.x * 256 + t;
    const int gsz = CSR_GRID * 256;

    // phase 0: zero count
    for (int i = gid; i < N_NODES; i += gsz) count[i] = 0;
    grid.sync();

    // phase 1: dst-degree histogram
    for (int e = gid; e < N_EDGES; e += gsz)
        atomicAdd(&count[ei[N_EDGES + e]], 1);
    grid.sync();

    // phase 2: per-256-chunk sums
    if (blockIdx.x < NBLK) {
        __shared__ int ws[4];
        int i = blockIdx.x * 256 + t;
        int v = (i < N_NODES) ? count[i] : 0;
        #pragma unroll
        for (int off = 32; off; off >>= 1) v += __shfl_down(v, off);
        if ((t & 63) == 0) ws[t >> 6] = v;
        __syncthreads();
        if (t == 0) blockSums[blockIdx.x] = ws[0] + ws[1] + ws[2] + ws[3];
    }
    grid.sync();

    // phase 3: exclusive scan of chunk sums (block 0)
    if (blockIdx.x == 0) {
        __shared__ int s[256];
        int v = (t < NBLK) ? blockSums[t] : 0;
        s[t] = v;
        __syncthreads();
        #pragma unroll
        for (int off = 1; off < 256; off <<= 1) {
            int u = (t >= off) ? s[t - off] : 0;
            __syncthreads();
            s[t] += u;
            __syncthreads();
        }
        if (t < NBLK) blockOffsets[t] = s[t] - v;
    }
    grid.sync();

    // phase 4: chunk-local scan -> offset; reset count (scatter cursor)
    if (blockIdx.x < NBLK) {
        __shared__ int s[256];
        int i = blockIdx.x * 256 + t;
        int c = (i < N_NODES) ? count[i] : 0;
        s[t] = c;
        __syncthreads();
        #pragma unroll
        for (int off = 1; off < 256; off <<= 1) {
            int u = (t >= off) ? s[t - off] : 0;
            __syncthreads();
            s[t] += u;
            __syncthreads();
        }
        if (i < N_NODES) {
            offset[i] = blockOffsets[blockIdx.x] + s[t] - c;
            count[i]  = 0;
        }
    }
    grid.sync();

    // phase 5: compute per-edge w once, scatter {src, w} into CSR order
    for (int e = gid; e < N_EDGES; e += gsz) {
        int s = ei[e];
        int d = ei[N_EDGES + e];
        float a  = es[s] + ed[d];
        float sg = 1.f / (1.f + __expf(-a));
        float w  = __expf(sg);
        int pos = offset[d] + atomicAdd(&count[d], 1);
        sortedSW[pos] = make_int2(s, __float_as_int(w));
    }
}

// ---------------- gather-aggregate: one wave/node, readlane broadcast, 8x MLP unroll
__global__ __launch_bounds__(256) void agg_kernel(
    const int2* __restrict__ sortedSW,
    const int* __restrict__ offset,
    const int* __restrict__ count,
    const unsigned short* __restrict__ hb,
    float* __restrict__ agg)
{
    int node = (blockIdx.x * 256 + threadIdx.x) >> 6;
    int lane = threadIdx.x & 63;
    if (node >= N_NODES) return;

    int beg = offset[node];
    int deg = count[node];

    float2 acc = make_float2(0.f, 0.f);
    float wsum = 0.f;

    for (int base = 0; base < deg; base += 64) {
        int cnt = min(64, deg - base);
        int2 sw = (lane < cnt) ? sortedSW[beg + base + lane] : make_int2(0, 0);

        // chunk weight sum (idle lanes contribute 0.0f)
        float wl = __uint_as_float((unsigned)sw.y);
        #pragma unroll
        for (int o = 32; o; o >>= 1) wl += __shfl_xor(wl, o);
        wsum += wl;

        int j = 0;
        for (; j + 8 <= cnt; j += 8) {
            int s0 = __builtin_amdgcn_readlane(sw.x, j + 0);
            int s1 = __builtin_amdgcn_readlane(sw.x, j + 1);
            int s2 = __builtin_amdgcn_readlane(sw.x, j + 2);
            int s3 = __builtin_amdgcn_readlane(sw.x, j + 3);
            int s4 = __builtin_amdgcn_readlane(sw.x, j + 4);
            int s5 = __builtin_amdgcn_readlane(sw.x, j + 5);
            int s6 = __builtin_amdgcn_readlane(sw.x, j + 6);
            int s7 = __builtin_amdgcn_readlane(sw.x, j + 7);
            unsigned u0 = *(const unsigned*)(hb + (size_t)s0 * DHID + 2 * lane);
            unsigned u1 = *(const unsigned*)(hb + (size_t)s1 * DHID + 2 * lane);
            unsigned u2 = *(const unsigned*)(hb + (size_t)s2 * DHID + 2 * lane);
            unsigned u3 = *(const unsigned*)(hb + (size_t)s3 * DHID + 2 * lane);
            unsigned u4 = *(const unsigned*)(hb + (size_t)s4 * DHID + 2 * lane);
            unsigned u5 = *(const unsigned*)(hb + (size_t)s5 * DHID + 2 * lane);
            unsigned u6 = *(const unsigned*)(hb + (size_t)s6 * DHID + 2 * lane);
            unsigned u7 = *(const unsigned*)(hb + (size_t)s7 * DHID + 2 * lane);
            float w0 = __uint_as_float((unsigned)__builtin_amdgcn_readlane(sw.y, j + 0));
            float w1 = __uint_as_float((unsigned)__builtin_amdgcn_readlane(sw.y, j + 1));
            float w2 = __uint_as_float((unsigned)__builtin_amdgcn_readlane(sw.y, j + 2));
            float w3 = __uint_as_float((unsigned)__builtin_amdgcn_readlane(sw.y, j + 3));
            float w4 = __uint_as_float((unsigned)__builtin_amdgcn_readlane(sw.y, j + 4));
            float w5 = __uint_as_float((unsigned)__builtin_amdgcn_readlane(sw.y, j + 5));
            float w6 = __uint_as_float((unsigned)__builtin_amdgcn_readlane(sw.y, j + 6));
            float w7 = __uint_as_float((unsigned)__builtin_amdgcn_readlane(sw.y, j + 7));
            acc.x += w0 * __uint_as_float(u0 << 16);
            acc.y += w0 * __uint_as_float(u0 & 0xffff0000u);
            acc.x += w1 * __uint_as_float(u1 << 16);
            acc.y += w1 * __uint_as_float(u1 & 0xffff0000u);
            acc.x += w2 * __uint_as_float(u2 << 16);
            acc.y += w2 * __uint_as_float(u2 & 0xffff0000u);
            acc.x += w3 * __uint_as_float(u3 << 16);
            acc.y += w3 * __uint_as_float(u3 & 0xffff0000u);
            acc.x += w4 * __uint_as_float(u4 << 16);
            acc.y += w4 * __uint_as_float(u4 & 0xffff0000u);
            acc.x += w5 * __uint_as_float(u5 << 16);
            acc.y += w5 * __uint_as_float(u5 & 0xffff0000u);
            acc.x += w6 * __uint_as_float(u6 << 16);
            acc.y += w6 * __uint_as_float(u6 & 0xffff0000u);
            acc.x += w7 * __uint_as_float(u7 << 16);
            acc.y += w7 * __uint_as_float(u7 & 0xffff0000u);
        }
        for (; j < cnt; ++j) {
            int   sj = __builtin_amdgcn_readlane(sw.x, j);
            float wj = __uint_as_float((unsigned)__builtin_amdgcn_readlane(sw.y, j));
            unsigned u = *(const unsigned*)(hb + (size_t)sj * DHID + 2 * lane);
            acc.x += wj * __uint_as_float(u << 16);
            acc.y += wj * __uint_as_float(u & 0xffff0000u);
        }
    }
    float inv = (deg > 0) ? 1.f / wsum : 0.f;
    ((float2*)(agg + (size_t)node * DHID))[lane] = make_float2(acc.x * inv, acc.y * inv);
}

// ---------------- gemm2: out(f32) = bf16(elu(agg)) @ W2t^T, MFMA, K=128.
__global__ __launch_bounds__(256) void gemm2_mfma(
    const float* __restrict__ agg,
    const unsigned short* __restrict__ W2t,
    float* __restrict__ out)
{
    __shared__ unsigned short W2s[DOUT * DHID];   // 32 KB

    const int tid = threadIdx.x;
    const int wave = tid >> 6, lane = tid & 63;
    const int row0 = blockIdx.x * 64 + wave * 16;
    const int m = lane & 15, q = lane >> 4;

    {
        const float4* src = (const float4*)W2t;
        float4* dst = (float4*)W2s;
        #pragma unroll
        for (int i = 0; i < 8; ++i)
            dst[tid + i * 256] = src[tid + i * 256];
    }
    __syncthreads();

    int r  = row0 + m;
    int rc = (r < N_NODES) ? r : 0;

    f32x4 acc[8];
    #pragma unroll
    for (int t = 0; t < 8; ++t) acc[t] = (f32x4){0.f, 0.f, 0.f, 0.f};

    const float* ar = agg + (size_t)rc * DHID + q * 8;
    const short* wp = (const short*)W2s + q * 8;

    #pragma unroll
    for (int kt = 0; kt < 4; ++kt) {
        float4 f0 = *(const float4*)(ar + kt * 32);
        float4 f1 = *(const float4*)(ar + kt * 32 + 4);
        float e0 = f0.x > 0.f ? f0.x : (__expf(f0.x) - 1.f);
        float e1 = f0.y > 0.f ? f0.y : (__expf(f0.y) - 1.f);
        float e2 = f0.z > 0.f ? f0.z : (__expf(f0.z) - 1.f);
        float e3 = f0.w > 0.f ? f0.w : (__expf(f0.w) - 1.f);
        float e4 = f1.x > 0.f ? f1.x : (__expf(f1.x) - 1.f);
        float e5 = f1.y > 0.f ? f1.y : (__expf(f1.y) - 1.f);
        float e6 = f1.z > 0.f ? f1.z : (__expf(f1.z) - 1.f);
        float e7 = f1.w > 0.f ? f1.w : (__expf(f1.w) - 1.f);
        bf16x8 a;
        a[0] = (short)f2b(e0); a[1] = (short)f2b(e1);
        a[2] = (short)f2b(e2); a[3] = (short)f2b(e3);
        a[4] = (short)f2b(e4); a[5] = (short)f2b(e5);
        a[6] = (short)f2b(e6); a[7] = (short)f2b(e7);
        #pragma unroll
        for (int t = 0; t < 8; ++t) {
            bf16x8 b = *(const bf16x8*)(wp + (t * 16 + m) * DHID + kt * 32);
            acc[t] = __builtin_amdgcn_mfma_f32_16x16x32_bf16(a, b, acc[t], 0, 0, 0);
        }
    }

    #pragma unroll
    for (int reg = 0; reg < 4; ++reg) {
        int rr = row0 + q * 4 + reg;
        if (rr < N_NODES) {
            #pragma unroll
            for (int t = 0; t < 8; ++t)
                out[(size_t)rr * DOUT + t * 16 + m] = acc[t][reg];
        }
    }
}

extern "C" void kernel_launch(void* const* d_in, const int* in_sizes, int n_in,
                              void* d_out, int out_size, void* d_ws, size_t ws_size,
                              hipStream_t stream)
{
    const float* x    = (const float*)d_in[0];
    const int*   ei   = (const int*)d_in[1];
    const float* W1   = (const float*)d_in[2];
    const float* asrc = (const float*)d_in[3];
    const float* adst = (const float*)d_in[4];
    const float* W2   = (const float*)d_in[5];
    float*       out  = (float*)d_out;

    // ---- workspace layout (~46 MB) ----
    char* p = (char*)d_ws;
    unsigned short* hb  = (unsigned short*)p;  p += (size_t)N_NODES * DHID * 2;  // 12.8 MB
    unsigned short* W1t = (unsigned short*)p;  p += (size_t)DHID * DIN * 2;      // 64 KB
    unsigned short* W2t = (unsigned short*)p;  p += (size_t)DOUT * DHID * 2;     // 32 KB
    float* es     = (float*)p;  p += (size_t)N_NODES * 4;
    float* ed     = (float*)p;  p += (size_t)N_NODES * 4;
    int*   count  = (int*)p;    p += (size_t)N_NODES * 4;
    int*   offset = (int*)p;    p += (size_t)N_NODES * 4;
    int*   blockSums    = (int*)p; p += 256 * 4;
    int*   blockOffsets = (int*)p; p += 256 * 4;
    int2*  sortedSW = (int2*)p; p += (size_t)N_EDGES * 8;                        // 6.4 MB
    float* agg      = (float*)p;                                                 // 25.6 MB

    convW_kernel<<<(DIN * DHID + DHID * DOUT) / 256, 256, 0, stream>>>(W1, W2, W1t, W2t);

    gemm1_mfma<<<(N_NODES + 63) / 64, 256, 0, stream>>>(x, W1t, asrc, adst, hb, es, ed);

    void* csr_args[] = { (void*)&ei, (void*)&es, (void*)&ed, (void*)&count,
                         (void*)&offset, (void*)&blockSums, (void*)&blockOffsets,
                         (void*)&sortedSW };
    hipLaunchCooperativeKernel((void*)csr_kernel, dim3(CSR_GRID), dim3(256),
                               csr_args, 0, stream);

    agg_kernel<<<(N_NODES * 64 + 255) / 256, 256, 0, stream>>>(
        sortedSW, offset, count, hb, agg);

    gemm2_mfma<<<(N_NODES + 63) / 64, 256, 0, stream>>>(agg, W2t, out);
}

// Round 8
// 244.723 us; speedup vs baseline: 2.5902x; 2.5902x over previous
//
#include <hip/hip_runtime.h>
#include <hip/hip_bf16.h>

#define N_NODES 50000
#define N_EDGES 800000
#define DIN 256
#define DHID 128
#define DOUT 128
#define NBLK 196   // ceil(N_NODES/256)

typedef __attribute__((ext_vector_type(8))) short bf16x8;
typedef __attribute__((ext_vector_type(4))) float f32x4;

__device__ inline unsigned short f2b(float f) {
    __hip_bfloat16 b = __float2bfloat16(f);
    return *reinterpret_cast<unsigned short*>(&b);
}

// ---------------- transpose+cast both weights in one dispatch
__global__ __launch_bounds__(256) void convW_kernel(
    const float* __restrict__ W1, const float* __restrict__ W2,
    unsigned short* __restrict__ W1t, unsigned short* __restrict__ W2t)
{
    int i = blockIdx.x * 256 + threadIdx.x;
    if (i < DIN * DHID) {
        int n = i >> 8, k = i & 255;
        W1t[i] = f2b(W1[k * DHID + n]);
    } else {
        int j = i - DIN * DHID;
        int n = j >> 7, k = j & 127;
        W2t[j] = f2b(W2[k * DOUT + n]);
    }
}

// ---------------- gemm1: hb = bf16( bf16(x) @ W1t^T ), MFMA 16x16x32.
// W1t staged in 64KB LDS; x read f32 + converted in-register.
// Fused epilogue: es = h.att_src, ed = h.att_dst.
__global__ __launch_bounds__(256) void gemm1_mfma(
    const float* __restrict__ x,
    const unsigned short* __restrict__ W1t,
    const float* __restrict__ att_src,
    const float* __restrict__ att_dst,
    unsigned short* __restrict__ hb,
    float* __restrict__ es,
    float* __restrict__ ed)
{
    __shared__ unsigned short W1s[DHID * DIN];   // 64 KB

    const int tid = threadIdx.x;
    const int wave = tid >> 6, lane = tid & 63;
    const int row0 = blockIdx.x * 64 + wave * 16;
    const int m = lane & 15, q = lane >> 4;

    {
        const float4* src = (const float4*)W1t;
        float4* dst = (float4*)W1s;
        #pragma unroll
        for (int i = 0; i < 16; ++i)
            dst[tid + i * 256] = src[tid + i * 256];
    }
    __syncthreads();

    int r  = row0 + m;
    int rc = (r < N_NODES) ? r : 0;

    f32x4 acc[8];
    #pragma unroll
    for (int t = 0; t < 8; ++t) acc[t] = (f32x4){0.f, 0.f, 0.f, 0.f};

    const float* xr = x + (size_t)rc * DIN + q * 8;
    const short* wp = (const short*)W1s + q * 8;

    #pragma unroll
    for (int kt = 0; kt < 8; ++kt) {
        float4 f0 = *(const float4*)(xr + kt * 32);
        float4 f1 = *(const float4*)(xr + kt * 32 + 4);
        bf16x8 a;
        a[0] = (short)f2b(f0.x); a[1] = (short)f2b(f0.y);
        a[2] = (short)f2b(f0.z); a[3] = (short)f2b(f0.w);
        a[4] = (short)f2b(f1.x); a[5] = (short)f2b(f1.y);
        a[6] = (short)f2b(f1.z); a[7] = (short)f2b(f1.w);
        #pragma unroll
        for (int t = 0; t < 8; ++t) {
            bf16x8 b = *(const bf16x8*)(wp + (t * 16 + m) * DIN + kt * 32);
            acc[t] = __builtin_amdgcn_mfma_f32_16x16x32_bf16(a, b, acc[t], 0, 0, 0);
        }
    }

    #pragma unroll
    for (int reg = 0; reg < 4; ++reg) {
        int rr = row0 + q * 4 + reg;
        if (rr < N_NODES) {
            #pragma unroll
            for (int t = 0; t < 8; ++t)
                hb[(size_t)rr * DHID + t * 16 + m] = f2b(acc[t][reg]);
        }
    }

    float esr[4] = {0.f, 0.f, 0.f, 0.f}, edr[4] = {0.f, 0.f, 0.f, 0.f};
    #pragma unroll
    for (int t = 0; t < 8; ++t) {
        float as = att_src[t * 16 + m];
        float ad = att_dst[t * 16 + m];
        #pragma unroll
        for (int reg = 0; reg < 4; ++reg) {
            esr[reg] += acc[t][reg] * as;
            edr[reg] += acc[t][reg] * ad;
        }
    }
    #pragma unroll
    for (int off = 8; off; off >>= 1)
        #pragma unroll
        for (int reg = 0; reg < 4; ++reg) {
            esr[reg] += __shfl_xor(esr[reg], off);
            edr[reg] += __shfl_xor(edr[reg], off);
        }
    if (m == 0) {
        #pragma unroll
        for (int reg = 0; reg < 4; ++reg) {
            int rr = row0 + q * 4 + reg;
            if (rr < N_NODES) { es[rr] = esr[reg]; ed[rr] = edr[reg]; }
        }
    }
}

// ---------------- histogram of dst degrees
__global__ __launch_bounds__(256) void hist_kernel(
    const int* __restrict__ ei, int* __restrict__ count)
{
    int e = blockIdx.x * 256 + threadIdx.x;
    if (e >= N_EDGES) return;
    atomicAdd(&count[ei[N_EDGES + e]], 1);
}

// ---------------- scan stage A: per-block sums
__global__ __launch_bounds__(256) void blocksum_kernel(
    const int* __restrict__ count, int* __restrict__ blockSums)
{
    __shared__ int ws[4];
    int t = threadIdx.x;
    int i = blockIdx.x * 256 + t;
    int v = (i < N_NODES) ? count[i] : 0;
    #pragma unroll
    for (int off = 32; off; off >>= 1) v += __shfl_down(v, off);
    if ((t & 63) == 0) ws[t >> 6] = v;
    __syncthreads();
    if (t == 0) blockSums[blockIdx.x] = ws[0] + ws[1] + ws[2] + ws[3];
}

// ---------------- scan stage B: exclusive scan of block sums (1 block)
__global__ __launch_bounds__(256) void scanb_kernel(
    const int* __restrict__ blockSums, int* __restrict__ blockOffsets)
{
    __shared__ int s[256];
    int t = threadIdx.x;
    int v = (t < NBLK) ? blockSums[t] : 0;
    s[t] = v;
    __syncthreads();
    #pragma unroll
    for (int off = 1; off < 256; off <<= 1) {
        int u = (t >= off) ? s[t - off] : 0;
        __syncthreads();
        s[t] += u;
        __syncthreads();
    }
    if (t < NBLK) blockOffsets[t] = s[t] - v;   // exclusive
}

// ---------------- scan stage C: block-local scan + global offset; zero count
__global__ __launch_bounds__(256) void scanc_kernel(
    int* __restrict__ count, const int* __restrict__ blockOffsets,
    int* __restrict__ offset)
{
    __shared__ int s[256];
    int t = threadIdx.x;
    int i = blockIdx.x * 256 + t;
    int c = (i < N_NODES) ? count[i] : 0;
    s[t] = c;
    __syncthreads();
    #pragma unroll
    for (int off = 1; off < 256; off <<= 1) {
        int u = (t >= off) ? s[t - off] : 0;
        __syncthreads();
        s[t] += u;
        __syncthreads();
    }
    if (i < N_NODES) {
        offset[i] = blockOffsets[blockIdx.x] + s[t] - c;   // exclusive prefix
        count[i] = 0;                                      // becomes scatter cursor
    }
}

// ---------------- scatter: compute per-edge w ONCE and scatter {src, w} into CSR order
__global__ __launch_bounds__(256) void scatter_kernel(
    const int* __restrict__ ei,
    const float* __restrict__ es,
    const float* __restrict__ ed,
    const int* __restrict__ offset,
    int* __restrict__ count,
    int2* __restrict__ sortedSW)
{
    int e = blockIdx.x * 256 + threadIdx.x;
    if (e >= N_EDGES) return;
    int s = ei[e];
    int d = ei[N_EDGES + e];
    float a  = es[s] + ed[d];               // es/ed: 200KB each, L2-resident
    float sg = 1.f / (1.f + __expf(-a));
    float w  = __expf(sg);
    int pos = offset[d] + atomicAdd(&count[d], 1);
    sortedSW[pos] = make_int2(s, __float_as_int(w));
}

// ---------------- gather-aggregate: one wave/node, readlane broadcast, 8x MLP unroll
__global__ __launch_bounds__(256) void agg_kernel(
    const int2* __restrict__ sortedSW,
    const int* __restrict__ offset,
    const int* __restrict__ count,
    const unsigned short* __restrict__ hb,
    float* __restrict__ agg)
{
    int node = (blockIdx.x * 256 + threadIdx.x) >> 6;
    int lane = threadIdx.x & 63;
    if (node >= N_NODES) return;

    int beg = offset[node];
    int deg = count[node];

    float2 acc = make_float2(0.f, 0.f);
    float wsum = 0.f;

    for (int base = 0; base < deg; base += 64) {
        int cnt = min(64, deg - base);
        int2 sw = (lane < cnt) ? sortedSW[beg + base + lane] : make_int2(0, 0);

        // chunk weight sum (idle lanes contribute 0.0f)
        float wl = __uint_as_float((unsigned)sw.y);
        #pragma unroll
        for (int o = 32; o; o >>= 1) wl += __shfl_xor(wl, o);
        wsum += wl;

        int j = 0;
        for (; j + 8 <= cnt; j += 8) {
            int s0 = __builtin_amdgcn_readlane(sw.x, j + 0);
            int s1 = __builtin_amdgcn_readlane(sw.x, j + 1);
            int s2 = __builtin_amdgcn_readlane(sw.x, j + 2);
            int s3 = __builtin_amdgcn_readlane(sw.x, j + 3);
            int s4 = __builtin_amdgcn_readlane(sw.x, j + 4);
            int s5 = __builtin_amdgcn_readlane(sw.x, j + 5);
            int s6 = __builtin_amdgcn_readlane(sw.x, j + 6);
            int s7 = __builtin_amdgcn_readlane(sw.x, j + 7);
            unsigned u0 = *(const unsigned*)(hb + (size_t)s0 * DHID + 2 * lane);
            unsigned u1 = *(const unsigned*)(hb + (size_t)s1 * DHID + 2 * lane);
            unsigned u2 = *(const unsigned*)(hb + (size_t)s2 * DHID + 2 * lane);
            unsigned u3 = *(const unsigned*)(hb + (size_t)s3 * DHID + 2 * lane);
            unsigned u4 = *(const unsigned*)(hb + (size_t)s4 * DHID + 2 * lane);
            unsigned u5 = *(const unsigned*)(hb + (size_t)s5 * DHID + 2 * lane);
            unsigned u6 = *(const unsigned*)(hb + (size_t)s6 * DHID + 2 * lane);
            unsigned u7 = *(const unsigned*)(hb + (size_t)s7 * DHID + 2 * lane);
            float w0 = __uint_as_float((unsigned)__builtin_amdgcn_readlane(sw.y, j + 0));
            float w1 = __uint_as_float((unsigned)__builtin_amdgcn_readlane(sw.y, j + 1));
            float w2 = __uint_as_float((unsigned)__builtin_amdgcn_readlane(sw.y, j + 2));
            float w3 = __uint_as_float((unsigned)__builtin_amdgcn_readlane(sw.y, j + 3));
            float w4 = __uint_as_float((unsigned)__builtin_amdgcn_readlane(sw.y, j + 4));
            float w5 = __uint_as_float((unsigned)__builtin_amdgcn_readlane(sw.y, j + 5));
            float w6 = __uint_as_float((unsigned)__builtin_amdgcn_readlane(sw.y, j + 6));
            float w7 = __uint_as_float((unsigned)__builtin_amdgcn_readlane(sw.y, j + 7));
            acc.x += w0 * __uint_as_float(u0 << 16);
            acc.y += w0 * __uint_as_float(u0 & 0xffff0000u);
            acc.x += w1 * __uint_as_float(u1 << 16);
            acc.y += w1 * __uint_as_float(u1 & 0xffff0000u);
            acc.x += w2 * __uint_as_float(u2 << 16);
            acc.y += w2 * __uint_as_float(u2 & 0xffff0000u);
            acc.x += w3 * __uint_as_float(u3 << 16);
            acc.y += w3 * __uint_as_float(u3 & 0xffff0000u);
            acc.x += w4 * __uint_as_float(u4 << 16);
            acc.y += w4 * __uint_as_float(u4 & 0xffff0000u);
            acc.x += w5 * __uint_as_float(u5 << 16);
            acc.y += w5 * __uint_as_float(u5 & 0xffff0000u);
            acc.x += w6 * __uint_as_float(u6 << 16);
            acc.y += w6 * __uint_as_float(u6 & 0xffff0000u);
            acc.x += w7 * __uint_as_float(u7 << 16);
            acc.y += w7 * __uint_as_float(u7 & 0xffff0000u);
        }
        for (; j < cnt; ++j) {
            int   sj = __builtin_amdgcn_readlane(sw.x, j);
            float wj = __uint_as_float((unsigned)__builtin_amdgcn_readlane(sw.y, j));
            unsigned u = *(const unsigned*)(hb + (size_t)sj * DHID + 2 * lane);
            acc.x += wj * __uint_as_float(u << 16);
            acc.y += wj * __uint_as_float(u & 0xffff0000u);
        }
    }
    float inv = (deg > 0) ? 1.f / wsum : 0.f;
    ((float2*)(agg + (size_t)node * DHID))[lane] = make_float2(acc.x * inv, acc.y * inv);
}

// ---------------- gemm2: out(f32) = bf16(elu(agg)) @ W2t^T, MFMA, K=128.
__global__ __launch_bounds__(256) void gemm2_mfma(
    const float* __restrict__ agg,
    const unsigned short* __restrict__ W2t,
    float* __restrict__ out)
{
    __shared__ unsigned short W2s[DOUT * DHID];   // 32 KB

    const int tid = threadIdx.x;
    const int wave = tid >> 6, lane = tid & 63;
    const int row0 = blockIdx.x * 64 + wave * 16;
    const int m = lane & 15, q = lane >> 4;

    {
        const float4* src = (const float4*)W2t;
        float4* dst = (float4*)W2s;
        #pragma unroll
        for (int i = 0; i < 8; ++i)
            dst[tid + i * 256] = src[tid + i * 256];
    }
    __syncthreads();

    int r  = row0 + m;
    int rc = (r < N_NODES) ? r : 0;

    f32x4 acc[8];
    #pragma unroll
    for (int t = 0; t < 8; ++t) acc[t] = (f32x4){0.f, 0.f, 0.f, 0.f};

    const float* ar = agg + (size_t)rc * DHID + q * 8;
    const short* wp = (const short*)W2s + q * 8;

    #pragma unroll
    for (int kt = 0; kt < 4; ++kt) {
        float4 f0 = *(const float4*)(ar + kt * 32);
        float4 f1 = *(const float4*)(ar + kt * 32 + 4);
        float e0 = f0.x > 0.f ? f0.x : (__expf(f0.x) - 1.f);
        float e1 = f0.y > 0.f ? f0.y : (__expf(f0.y) - 1.f);
        float e2 = f0.z > 0.f ? f0.z : (__expf(f0.z) - 1.f);
        float e3 = f0.w > 0.f ? f0.w : (__expf(f0.w) - 1.f);
        float e4 = f1.x > 0.f ? f1.x : (__expf(f1.x) - 1.f);
        float e5 = f1.y > 0.f ? f1.y : (__expf(f1.y) - 1.f);
        float e6 = f1.z > 0.f ? f1.z : (__expf(f1.z) - 1.f);
        float e7 = f1.w > 0.f ? f1.w : (__expf(f1.w) - 1.f);
        bf16x8 a;
        a[0] = (short)f2b(e0); a[1] = (short)f2b(e1);
        a[2] = (short)f2b(e2); a[3] = (short)f2b(e3);
        a[4] = (short)f2b(e4); a[5] = (short)f2b(e5);
        a[6] = (short)f2b(e6); a[7] = (short)f2b(e7);
        #pragma unroll
        for (int t = 0; t < 8; ++t) {
            bf16x8 b = *(const bf16x8*)(wp + (t * 16 + m) * DHID + kt * 32);
            acc[t] = __builtin_amdgcn_mfma_f32_16x16x32_bf16(a, b, acc[t], 0, 0, 0);
        }
    }

    #pragma unroll
    for (int reg = 0; reg < 4; ++reg) {
        int rr = row0 + q * 4 + reg;
        if (rr < N_NODES) {
            #pragma unroll
            for (int t = 0; t < 8; ++t)
                out[(size_t)rr * DOUT + t * 16 + m] = acc[t][reg];
        }
    }
}

extern "C" void kernel_launch(void* const* d_in, const int* in_sizes, int n_in,
                              void* d_out, int out_size, void* d_ws, size_t ws_size,
                              hipStream_t stream)
{
    const float* x    = (const float*)d_in[0];
    const int*   ei   = (const int*)d_in[1];
    const float* W1   = (const float*)d_in[2];
    const float* asrc = (const float*)d_in[3];
    const float* adst = (const float*)d_in[4];
    const float* W2   = (const float*)d_in[5];
    float*       out  = (float*)d_out;

    // ---- workspace layout (~46 MB) ----
    char* p = (char*)d_ws;
    unsigned short* hb  = (unsigned short*)p;  p += (size_t)N_NODES * DHID * 2;  // 12.8 MB
    unsigned short* W1t = (unsigned short*)p;  p += (size_t)DHID * DIN * 2;      // 64 KB
    unsigned short* W2t = (unsigned short*)p;  p += (size_t)DOUT * DHID * 2;     // 32 KB
    float* es     = (float*)p;  p += (size_t)N_NODES * 4;
    float* ed     = (float*)p;  p += (size_t)N_NODES * 4;
    int*   count  = (int*)p;    p += (size_t)N_NODES * 4;
    int*   offset = (int*)p;    p += (size_t)N_NODES * 4;
    int*   blockSums    = (int*)p; p += 256 * 4;
    int*   blockOffsets = (int*)p; p += 256 * 4;
    int2*  sortedSW = (int2*)p; p += (size_t)N_EDGES * 8;                        // 6.4 MB
    float* agg      = (float*)p;                                                 // 25.6 MB

    hipMemsetAsync(count, 0, sizeof(int) * N_NODES, stream);

    convW_kernel<<<(DIN * DHID + DHID * DOUT) / 256, 256, 0, stream>>>(W1, W2, W1t, W2t);

    gemm1_mfma<<<(N_NODES + 63) / 64, 256, 0, stream>>>(x, W1t, asrc, adst, hb, es, ed);

    hist_kernel    <<<(N_EDGES + 255) / 256, 256, 0, stream>>>(ei, count);
    blocksum_kernel<<<NBLK, 256, 0, stream>>>(count, blockSums);
    scanb_kernel   <<<1, 256, 0, stream>>>(blockSums, blockOffsets);
    scanc_kernel   <<<NBLK, 256, 0, stream>>>(count, blockOffsets, offset);
    scatter_kernel <<<(N_EDGES + 255) / 256, 256, 0, stream>>>(
        ei, es, ed, offset, count, sortedSW);

    agg_kernel<<<(N_NODES * 64 + 255) / 256, 256, 0, stream>>>(
        sortedSW, offset, count, hb, agg);

    gemm2_mfma<<<(N_NODES + 63) / 64, 256, 0, stream>>>(agg, W2t, out);
}

// Round 9
// 197.518 us; speedup vs baseline: 3.2093x; 1.2390x over previous
//
#include <hip/hip_runtime.h>
#include <hip/hip_bf16.h>

#define N_NODES 50000
#define N_EDGES 800000
#define DIN 256
#define DHID 128
#define DOUT 128
#define NBUCK 196     // buckets = dst >> 8  (50000/256 -> 196)
#define BINBLK 256    // binning blocks
#define EPB 3125      // edges per binning block (256*3125 = 800000 exact)
#define BINIT 13      // ceil(3125/256)

typedef __attribute__((ext_vector_type(8))) short bf16x8;
typedef __attribute__((ext_vector_type(4))) float f32x4;

__device__ inline unsigned short f2b(float f) {
    __hip_bfloat16 b = __float2bfloat16(f);
    return *reinterpret_cast<unsigned short*>(&b);
}

// ---------------- transpose+cast both weights in one dispatch
__global__ __launch_bounds__(256) void convW_kernel(
    const float* __restrict__ W1, const float* __restrict__ W2,
    unsigned short* __restrict__ W1t, unsigned short* __restrict__ W2t)
{
    int i = blockIdx.x * 256 + threadIdx.x;
    if (i < DIN * DHID) {
        int n = i >> 8, k = i & 255;
        W1t[i] = f2b(W1[k * DHID + n]);
    } else {
        int j = i - DIN * DHID;
        int n = j >> 7, k = j & 127;
        W2t[j] = f2b(W2[k * DOUT + n]);
    }
}

// ---------------- gemm1: hb = bf16( bf16(x) @ W1t^T ), MFMA 16x16x32.
// W1t staged in 64KB LDS; fused epilogue computes es/ed.
__global__ __launch_bounds__(256) void gemm1_mfma(
    const float* __restrict__ x,
    const unsigned short* __restrict__ W1t,
    const float* __restrict__ att_src,
    const float* __restrict__ att_dst,
    unsigned short* __restrict__ hb,
    float* __restrict__ es,
    float* __restrict__ ed)
{
    __shared__ unsigned short W1s[DHID * DIN];   // 64 KB

    const int tid = threadIdx.x;
    const int wave = tid >> 6, lane = tid & 63;
    const int row0 = blockIdx.x * 64 + wave * 16;
    const int m = lane & 15, q = lane >> 4;

    {
        const float4* src = (const float4*)W1t;
        float4* dst = (float4*)W1s;
        #pragma unroll
        for (int i = 0; i < 16; ++i)
            dst[tid + i * 256] = src[tid + i * 256];
    }
    __syncthreads();

    int r  = row0 + m;
    int rc = (r < N_NODES) ? r : 0;

    f32x4 acc[8];
    #pragma unroll
    for (int t = 0; t < 8; ++t) acc[t] = (f32x4){0.f, 0.f, 0.f, 0.f};

    const float* xr = x + (size_t)rc * DIN + q * 8;
    const short* wp = (const short*)W1s + q * 8;

    #pragma unroll
    for (int kt = 0; kt < 8; ++kt) {
        float4 f0 = *(const float4*)(xr + kt * 32);
        float4 f1 = *(const float4*)(xr + kt * 32 + 4);
        bf16x8 a;
        a[0] = (short)f2b(f0.x); a[1] = (short)f2b(f0.y);
        a[2] = (short)f2b(f0.z); a[3] = (short)f2b(f0.w);
        a[4] = (short)f2b(f1.x); a[5] = (short)f2b(f1.y);
        a[6] = (short)f2b(f1.z); a[7] = (short)f2b(f1.w);
        #pragma unroll
        for (int t = 0; t < 8; ++t) {
            bf16x8 b = *(const bf16x8*)(wp + (t * 16 + m) * DIN + kt * 32);
            acc[t] = __builtin_amdgcn_mfma_f32_16x16x32_bf16(a, b, acc[t], 0, 0, 0);
        }
    }

    #pragma unroll
    for (int reg = 0; reg < 4; ++reg) {
        int rr = row0 + q * 4 + reg;
        if (rr < N_NODES) {
            #pragma unroll
            for (int t = 0; t < 8; ++t)
                hb[(size_t)rr * DHID + t * 16 + m] = f2b(acc[t][reg]);
        }
    }

    float esr[4] = {0.f, 0.f, 0.f, 0.f}, edr[4] = {0.f, 0.f, 0.f, 0.f};
    #pragma unroll
    for (int t = 0; t < 8; ++t) {
        float as = att_src[t * 16 + m];
        float ad = att_dst[t * 16 + m];
        #pragma unroll
        for (int reg = 0; reg < 4; ++reg) {
            esr[reg] += acc[t][reg] * as;
            edr[reg] += acc[t][reg] * ad;
        }
    }
    #pragma unroll
    for (int off = 8; off; off >>= 1)
        #pragma unroll
        for (int reg = 0; reg < 4; ++reg) {
            esr[reg] += __shfl_xor(esr[reg], off);
            edr[reg] += __shfl_xor(edr[reg], off);
        }
    if (m == 0) {
        #pragma unroll
        for (int reg = 0; reg < 4; ++reg) {
            int rr = row0 + q * 4 + reg;
            if (rr < N_NODES) { es[rr] = esr[reg]; ed[rr] = edr[reg]; }
        }
    }
}

// ---------------- per-block bucket histogram: blockHist[bucket*256 + blk]
__global__ __launch_bounds__(256) void lhist_kernel(
    const int* __restrict__ ei, int* __restrict__ blockHist)
{
    __shared__ int h[NBUCK];
    const int t = threadIdx.x, blk = blockIdx.x;
    if (t < NBUCK) h[t] = 0;
    __syncthreads();
    const int base = blk * EPB;
    #pragma unroll 1
    for (int it = 0; it < BINIT; ++it) {
        int e = base + it * 256 + t;
        if (e < base + EPB)
            atomicAdd(&h[ei[N_EDGES + e] >> 8], 1);
    }
    __syncthreads();
    if (t < NBUCK) blockHist[t * 256 + blk] = h[t];
}

// ---------------- scan stage A over the 196*256 matrix: per-256-chunk sums
__global__ __launch_bounds__(256) void blocksum_kernel(
    const int* __restrict__ in, int* __restrict__ blockSums)
{
    __shared__ int ws[4];
    int t = threadIdx.x;
    int v = in[blockIdx.x * 256 + t];          // 196*256 exact, no guard
    #pragma unroll
    for (int off = 32; off; off >>= 1) v += __shfl_down(v, off);
    if ((t & 63) == 0) ws[t >> 6] = v;
    __syncthreads();
    if (t == 0) blockSums[blockIdx.x] = ws[0] + ws[1] + ws[2] + ws[3];
}

// ---------------- scan stage B: exclusive scan of 196 chunk sums (1 block)
__global__ __launch_bounds__(256) void scanb_kernel(
    const int* __restrict__ blockSums, int* __restrict__ blockOffsets)
{
    __shared__ int s[256];
    int t = threadIdx.x;
    int v = (t < NBUCK) ? blockSums[t] : 0;
    s[t] = v;
    __syncthreads();
    #pragma unroll
    for (int off = 1; off < 256; off <<= 1) {
        int u = (t >= off) ? s[t - off] : 0;
        __syncthreads();
        s[t] += u;
        __syncthreads();
    }
    if (t < NBUCK) blockOffsets[t] = s[t] - v;   // exclusive
}

// ---------------- scan stage C: chunk-local scan + chunk offset -> matrixScan
__global__ __launch_bounds__(256) void scanc_kernel(
    const int* __restrict__ in, const int* __restrict__ blockOffsets,
    int* __restrict__ outScan)
{
    __shared__ int s[256];
    int t = threadIdx.x;
    int i = blockIdx.x * 256 + t;
    int c = in[i];
    s[t] = c;
    __syncthreads();
    #pragma unroll
    for (int off = 1; off < 256; off <<= 1) {
        int u = (t >= off) ? s[t - off] : 0;
        __syncthreads();
        s[t] += u;
        __syncthreads();
    }
    outScan[i] = blockOffsets[blockIdx.x] + s[t] - c;   // exclusive prefix
}

// ---------------- binpass: deterministic multi-split. Each (block,bucket) owns a
// private contiguous range of binned[] -> all writes to a line come from one XCD.
__global__ __launch_bounds__(256) void binpass_kernel(
    const int* __restrict__ ei,
    const float* __restrict__ es,
    const float* __restrict__ ed,
    const int* __restrict__ matrixScan,
    int2* __restrict__ binned)
{
    __shared__ int lcur[NBUCK];
    const int t = threadIdx.x, blk = blockIdx.x;
    if (t < NBUCK) lcur[t] = matrixScan[t * 256 + blk];
    __syncthreads();
    const int base = blk * EPB;
    #pragma unroll 1
    for (int it = 0; it < BINIT; ++it) {
        int e = base + it * 256 + t;
        if (e < base + EPB) {
            int s = ei[e];
            int d = ei[N_EDGES + e];
            float a  = es[s] + ed[d];
            float sg = 1.f / (1.f + __expf(-a));
            float w  = __expf(sg);
            int pos = atomicAdd(&lcur[d >> 8], 1);
            binned[pos] = make_int2(s | ((d & 255) << 16), __float_as_int(w));
        }
    }
}

// ---------------- sortpass: one block per bucket. Hist over dlow, scan, write
// offset[]/count[], place entries into sortedSW (bucket region is XCD-private).
__global__ __launch_bounds__(256) void sortpass_kernel(
    const int2* __restrict__ binned,
    const int* __restrict__ matrixScan,
    int2* __restrict__ sortedSW,
    int* __restrict__ offset,
    int* __restrict__ count)
{
    __shared__ int lhist[256], lscan[256], lcur[256];
    const int t = threadIdx.x, b = blockIdx.x;
    const int start = matrixScan[b * 256];
    const int end   = (b == NBUCK - 1) ? N_EDGES : matrixScan[(b + 1) * 256];
    const int cnt   = end - start;

    lhist[t] = 0;
    __syncthreads();
    for (int i = t; i < cnt; i += 256)
        atomicAdd(&lhist[(binned[start + i].x >> 16) & 255], 1);
    __syncthreads();

    int v = lhist[t];
    lscan[t] = v;
    __syncthreads();
    #pragma unroll
    for (int off = 1; off < 256; off <<= 1) {
        int u = (t >= off) ? lscan[t - off] : 0;
        __syncthreads();
        lscan[t] += u;
        __syncthreads();
    }
    int excl = lscan[t] - v;

    int node = (b << 8) + t;
    if (node < N_NODES) { offset[node] = start + excl; count[node] = v; }
    lcur[t] = excl;
    __syncthreads();

    for (int i = t; i < cnt; i += 256) {
        int2 ent = binned[start + i];
        int dlow = (ent.x >> 16) & 255;
        int pos = atomicAdd(&lcur[dlow], 1);
        sortedSW[start + pos] = make_int2(ent.x & 0xFFFF, ent.y);
    }
}

// ---------------- gather-aggregate: one wave/node, readlane broadcast, 8x MLP unroll
__global__ __launch_bounds__(256) void agg_kernel(
    const int2* __restrict__ sortedSW,
    const int* __restrict__ offset,
    const int* __restrict__ count,
    const unsigned short* __restrict__ hb,
    float* __restrict__ agg)
{
    int node = (blockIdx.x * 256 + threadIdx.x) >> 6;
    int lane = threadIdx.x & 63;
    if (node >= N_NODES) return;

    int beg = offset[node];
    int deg = count[node];

    float2 acc = make_float2(0.f, 0.f);
    float wsum = 0.f;

    for (int base = 0; base < deg; base += 64) {
        int cnt = min(64, deg - base);
        int2 sw = (lane < cnt) ? sortedSW[beg + base + lane] : make_int2(0, 0);

        float wl = __uint_as_float((unsigned)sw.y);
        #pragma unroll
        for (int o = 32; o; o >>= 1) wl += __shfl_xor(wl, o);
        wsum += wl;

        int j = 0;
        for (; j + 8 <= cnt; j += 8) {
            int s0 = __builtin_amdgcn_readlane(sw.x, j + 0);
            int s1 = __builtin_amdgcn_readlane(sw.x, j + 1);
            int s2 = __builtin_amdgcn_readlane(sw.x, j + 2);
            int s3 = __builtin_amdgcn_readlane(sw.x, j + 3);
            int s4 = __builtin_amdgcn_readlane(sw.x, j + 4);
            int s5 = __builtin_amdgcn_readlane(sw.x, j + 5);
            int s6 = __builtin_amdgcn_readlane(sw.x, j + 6);
            int s7 = __builtin_amdgcn_readlane(sw.x, j + 7);
            unsigned u0 = *(const unsigned*)(hb + (size_t)s0 * DHID + 2 * lane);
            unsigned u1 = *(const unsigned*)(hb + (size_t)s1 * DHID + 2 * lane);
            unsigned u2 = *(const unsigned*)(hb + (size_t)s2 * DHID + 2 * lane);
            unsigned u3 = *(const unsigned*)(hb + (size_t)s3 * DHID + 2 * lane);
            unsigned u4 = *(const unsigned*)(hb + (size_t)s4 * DHID + 2 * lane);
            unsigned u5 = *(const unsigned*)(hb + (size_t)s5 * DHID + 2 * lane);
            unsigned u6 = *(const unsigned*)(hb + (size_t)s6 * DHID + 2 * lane);
            unsigned u7 = *(const unsigned*)(hb + (size_t)s7 * DHID + 2 * lane);
            float w0 = __uint_as_float((unsigned)__builtin_amdgcn_readlane(sw.y, j + 0));
            float w1 = __uint_as_float((unsigned)__builtin_amdgcn_readlane(sw.y, j + 1));
            float w2 = __uint_as_float((unsigned)__builtin_amdgcn_readlane(sw.y, j + 2));
            float w3 = __uint_as_float((unsigned)__builtin_amdgcn_readlane(sw.y, j + 3));
            float w4 = __uint_as_float((unsigned)__builtin_amdgcn_readlane(sw.y, j + 4));
            float w5 = __uint_as_float((unsigned)__builtin_amdgcn_readlane(sw.y, j + 5));
            float w6 = __uint_as_float((unsigned)__builtin_amdgcn_readlane(sw.y, j + 6));
            float w7 = __uint_as_float((unsigned)__builtin_amdgcn_readlane(sw.y, j + 7));
            acc.x += w0 * __uint_as_float(u0 << 16);
            acc.y += w0 * __uint_as_float(u0 & 0xffff0000u);
            acc.x += w1 * __uint_as_float(u1 << 16);
            acc.y += w1 * __uint_as_float(u1 & 0xffff0000u);
            acc.x += w2 * __uint_as_float(u2 << 16);
            acc.y += w2 * __uint_as_float(u2 & 0xffff0000u);
            acc.x += w3 * __uint_as_float(u3 << 16);
            acc.y += w3 * __uint_as_float(u3 & 0xffff0000u);
            acc.x += w4 * __uint_as_float(u4 << 16);
            acc.y += w4 * __uint_as_float(u4 & 0xffff0000u);
            acc.x += w5 * __uint_as_float(u5 << 16);
            acc.y += w5 * __uint_as_float(u5 & 0xffff0000u);
            acc.x += w6 * __uint_as_float(u6 << 16);
            acc.y += w6 * __uint_as_float(u6 & 0xffff0000u);
            acc.x += w7 * __uint_as_float(u7 << 16);
            acc.y += w7 * __uint_as_float(u7 & 0xffff0000u);
        }
        for (; j < cnt; ++j) {
            int   sj = __builtin_amdgcn_readlane(sw.x, j);
            float wj = __uint_as_float((unsigned)__builtin_amdgcn_readlane(sw.y, j));
            unsigned u = *(const unsigned*)(hb + (size_t)sj * DHID + 2 * lane);
            acc.x += wj * __uint_as_float(u << 16);
            acc.y += wj * __uint_as_float(u & 0xffff0000u);
        }
    }
    float inv = (deg > 0) ? 1.f / wsum : 0.f;
    ((float2*)(agg + (size_t)node * DHID))[lane] = make_float2(acc.x * inv, acc.y * inv);
}

// ---------------- gemm2: out(f32) = bf16(elu(agg)) @ W2t^T, MFMA, K=128.
__global__ __launch_bounds__(256) void gemm2_mfma(
    const float* __restrict__ agg,
    const unsigned short* __restrict__ W2t,
    float* __restrict__ out)
{
    __shared__ unsigned short W2s[DOUT * DHID];   // 32 KB

    const int tid = threadIdx.x;
    const int wave = tid >> 6, lane = tid & 63;
    const int row0 = blockIdx.x * 64 + wave * 16;
    const int m = lane & 15, q = lane >> 4;

    {
        const float4* src = (const float4*)W2t;
        float4* dst = (float4*)W2s;
        #pragma unroll
        for (int i = 0; i < 8; ++i)
            dst[tid + i * 256] = src[tid + i * 256];
    }
    __syncthreads();

    int r  = row0 + m;
    int rc = (r < N_NODES) ? r : 0;

    f32x4 acc[8];
    #pragma unroll
    for (int t = 0; t < 8; ++t) acc[t] = (f32x4){0.f, 0.f, 0.f, 0.f};

    const float* ar = agg + (size_t)rc * DHID + q * 8;
    const short* wp = (const short*)W2s + q * 8;

    #pragma unroll
    for (int kt = 0; kt < 4; ++kt) {
        float4 f0 = *(const float4*)(ar + kt * 32);
        float4 f1 = *(const float4*)(ar + kt * 32 + 4);
        float e0 = f0.x > 0.f ? f0.x : (__expf(f0.x) - 1.f);
        float e1 = f0.y > 0.f ? f0.y : (__expf(f0.y) - 1.f);
        float e2 = f0.z > 0.f ? f0.z : (__expf(f0.z) - 1.f);
        float e3 = f0.w > 0.f ? f0.w : (__expf(f0.w) - 1.f);
        float e4 = f1.x > 0.f ? f1.x : (__expf(f1.x) - 1.f);
        float e5 = f1.y > 0.f ? f1.y : (__expf(f1.y) - 1.f);
        float e6 = f1.z > 0.f ? f1.z : (__expf(f1.z) - 1.f);
        float e7 = f1.w > 0.f ? f1.w : (__expf(f1.w) - 1.f);
        bf16x8 a;
        a[0] = (short)f2b(e0); a[1] = (short)f2b(e1);
        a[2] = (short)f2b(e2); a[3] = (short)f2b(e3);
        a[4] = (short)f2b(e4); a[5] = (short)f2b(e5);
        a[6] = (short)f2b(e6); a[7] = (short)f2b(e7);
        #pragma unroll
        for (int t = 0; t < 8; ++t) {
            bf16x8 b = *(const bf16x8*)(wp + (t * 16 + m) * DHID + kt * 32);
            acc[t] = __builtin_amdgcn_mfma_f32_16x16x32_bf16(a, b, acc[t], 0, 0, 0);
        }
    }

    #pragma unroll
    for (int reg = 0; reg < 4; ++reg) {
        int rr = row0 + q * 4 + reg;
        if (rr < N_NODES) {
            #pragma unroll
            for (int t = 0; t < 8; ++t)
                out[(size_t)rr * DOUT + t * 16 + m] = acc[t][reg];
        }
    }
}

extern "C" void kernel_launch(void* const* d_in, const int* in_sizes, int n_in,
                              void* d_out, int out_size, void* d_ws, size_t ws_size,
                              hipStream_t stream)
{
    const float* x    = (const float*)d_in[0];
    const int*   ei   = (const int*)d_in[1];
    const float* W1   = (const float*)d_in[2];
    const float* asrc = (const float*)d_in[3];
    const float* adst = (const float*)d_in[4];
    const float* W2   = (const float*)d_in[5];
    float*       out  = (float*)d_out;

    // ---- workspace layout (~53 MB) ----
    char* p = (char*)d_ws;
    unsigned short* hb  = (unsigned short*)p;  p += (size_t)N_NODES * DHID * 2;  // 12.8 MB
    unsigned short* W1t = (unsigned short*)p;  p += (size_t)DHID * DIN * 2;      // 64 KB
    unsigned short* W2t = (unsigned short*)p;  p += (size_t)DOUT * DHID * 2;     // 32 KB
    float* es     = (float*)p;  p += (size_t)N_NODES * 4;
    float* ed     = (float*)p;  p += (size_t)N_NODES * 4;
    int*   offset = (int*)p;    p += (size_t)N_NODES * 4;
    int*   count  = (int*)p;    p += (size_t)N_NODES * 4;
    int*   blockHist    = (int*)p; p += (size_t)NBUCK * 256 * 4;                 // 200 KB
    int*   matrixScan   = (int*)p; p += (size_t)NBUCK * 256 * 4;                 // 200 KB
    int*   blockSums    = (int*)p; p += 256 * 4;
    int*   blockOffsets = (int*)p; p += 256 * 4;
    int2*  binned   = (int2*)p; p += (size_t)N_EDGES * 8;                        // 6.4 MB
    int2*  sortedSW = (int2*)p; p += (size_t)N_EDGES * 8;                        // 6.4 MB
    float* agg      = (float*)p;                                                 // 25.6 MB

    convW_kernel<<<(DIN * DHID + DHID * DOUT) / 256, 256, 0, stream>>>(W1, W2, W1t, W2t);

    gemm1_mfma<<<(N_NODES + 63) / 64, 256, 0, stream>>>(x, W1t, asrc, adst, hb, es, ed);

    // CSR build via deterministic multi-split (no global atomics, XCD-local writes)
    lhist_kernel   <<<BINBLK, 256, 0, stream>>>(ei, blockHist);
    blocksum_kernel<<<NBUCK, 256, 0, stream>>>(blockHist, blockSums);
    scanb_kernel   <<<1, 256, 0, stream>>>(blockSums, blockOffsets);
    scanc_kernel   <<<NBUCK, 256, 0, stream>>>(blockHist, blockOffsets, matrixScan);
    binpass_kernel <<<BINBLK, 256, 0, stream>>>(ei, es, ed, matrixScan, binned);
    sortpass_kernel<<<NBUCK, 256, 0, stream>>>(binned, matrixScan, sortedSW, offset, count);

    agg_kernel<<<(N_NODES * 64 + 255) / 256, 256, 0, stream>>>(
        sortedSW, offset, count, hb, agg);

    gemm2_mfma<<<(N_NODES + 63) / 64, 256, 0, stream>>>(agg, W2t, out);
}

// Round 10
// 195.162 us; speedup vs baseline: 3.2480x; 1.0121x over previous
//
#include <hip/hip_runtime.h>
#include <hip/hip_bf16.h>

#define N_NODES 50000
#define N_EDGES 800000
#define DIN 256
#define DHID 128
#define DOUT 128
#define NBUCK 196     // buckets = dst >> 8
#define BINBLK 256    // binning blocks
#define EPB 3125      // edges per binning block (256*3125 = 800000 exact)
#define BINIT 13      // ceil(3125/256)

typedef __attribute__((ext_vector_type(8))) short bf16x8;
typedef __attribute__((ext_vector_type(4))) float f32x4;

__device__ inline unsigned short f2b(float f) {
    __hip_bfloat16 b = __float2bfloat16(f);
    return *reinterpret_cast<unsigned short*>(&b);
}

// ---------------- transpose+cast both weights in one dispatch
__global__ __launch_bounds__(256) void convW_kernel(
    const float* __restrict__ W1, const float* __restrict__ W2,
    unsigned short* __restrict__ W1t, unsigned short* __restrict__ W2t)
{
    int i = blockIdx.x * 256 + threadIdx.x;
    if (i < DIN * DHID) {
        int n = i >> 8, k = i & 255;
        W1t[i] = f2b(W1[k * DHID + n]);
    } else {
        int j = i - DIN * DHID;
        int n = j >> 7, k = j & 127;
        W2t[j] = f2b(W2[k * DOUT + n]);
    }
}

// ---------------- gemm1: hb = bf16( bf16(x) @ W1t^T ), MFMA 16x16x32.
// W1t staged in 64KB LDS; fused epilogue computes es/ed.
__global__ __launch_bounds__(256) void gemm1_mfma(
    const float* __restrict__ x,
    const unsigned short* __restrict__ W1t,
    const float* __restrict__ att_src,
    const float* __restrict__ att_dst,
    unsigned short* __restrict__ hb,
    float* __restrict__ es,
    float* __restrict__ ed)
{
    __shared__ unsigned short W1s[DHID * DIN];   // 64 KB

    const int tid = threadIdx.x;
    const int wave = tid >> 6, lane = tid & 63;
    const int row0 = blockIdx.x * 64 + wave * 16;
    const int m = lane & 15, q = lane >> 4;

    {
        const float4* src = (const float4*)W1t;
        float4* dst = (float4*)W1s;
        #pragma unroll
        for (int i = 0; i < 16; ++i)
            dst[tid + i * 256] = src[tid + i * 256];
    }
    __syncthreads();

    int r  = row0 + m;
    int rc = (r < N_NODES) ? r : 0;

    f32x4 acc[8];
    #pragma unroll
    for (int t = 0; t < 8; ++t) acc[t] = (f32x4){0.f, 0.f, 0.f, 0.f};

    const float* xr = x + (size_t)rc * DIN + q * 8;
    const short* wp = (const short*)W1s + q * 8;

    #pragma unroll
    for (int kt = 0; kt < 8; ++kt) {
        float4 f0 = *(const float4*)(xr + kt * 32);
        float4 f1 = *(const float4*)(xr + kt * 32 + 4);
        bf16x8 a;
        a[0] = (short)f2b(f0.x); a[1] = (short)f2b(f0.y);
        a[2] = (short)f2b(f0.z); a[3] = (short)f2b(f0.w);
        a[4] = (short)f2b(f1.x); a[5] = (short)f2b(f1.y);
        a[6] = (short)f2b(f1.z); a[7] = (short)f2b(f1.w);
        #pragma unroll
        for (int t = 0; t < 8; ++t) {
            bf16x8 b = *(const bf16x8*)(wp + (t * 16 + m) * DIN + kt * 32);
            acc[t] = __builtin_amdgcn_mfma_f32_16x16x32_bf16(a, b, acc[t], 0, 0, 0);
        }
    }

    #pragma unroll
    for (int reg = 0; reg < 4; ++reg) {
        int rr = row0 + q * 4 + reg;
        if (rr < N_NODES) {
            #pragma unroll
            for (int t = 0; t < 8; ++t)
                hb[(size_t)rr * DHID + t * 16 + m] = f2b(acc[t][reg]);
        }
    }

    float esr[4] = {0.f, 0.f, 0.f, 0.f}, edr[4] = {0.f, 0.f, 0.f, 0.f};
    #pragma unroll
    for (int t = 0; t < 8; ++t) {
        float as = att_src[t * 16 + m];
        float ad = att_dst[t * 16 + m];
        #pragma unroll
        for (int reg = 0; reg < 4; ++reg) {
            esr[reg] += acc[t][reg] * as;
            edr[reg] += acc[t][reg] * ad;
        }
    }
    #pragma unroll
    for (int off = 8; off; off >>= 1)
        #pragma unroll
        for (int reg = 0; reg < 4; ++reg) {
            esr[reg] += __shfl_xor(esr[reg], off);
            edr[reg] += __shfl_xor(edr[reg], off);
        }
    if (m == 0) {
        #pragma unroll
        for (int reg = 0; reg < 4; ++reg) {
            int rr = row0 + q * 4 + reg;
            if (rr < N_NODES) { es[rr] = esr[reg]; ed[rr] = edr[reg]; }
        }
    }
}

// ---------------- per-block bucket histogram + global bucket totals
__global__ __launch_bounds__(256) void lhist_kernel(
    const int* __restrict__ ei, int* __restrict__ blockHist,
    int* __restrict__ bucketTotals)
{
    __shared__ int h[NBUCK];
    const int t = threadIdx.x, blk = blockIdx.x;
    if (t < NBUCK) h[t] = 0;
    __syncthreads();
    const int base = blk * EPB;
    #pragma unroll 1
    for (int it = 0; it < BINIT; ++it) {
        int e = base + it * 256 + t;
        if (e < base + EPB)
            atomicAdd(&h[ei[N_EDGES + e] >> 8], 1);
    }
    __syncthreads();
    if (t < NBUCK) {
        blockHist[t * 256 + blk] = h[t];
        atomicAdd(&bucketTotals[t], h[t]);
    }
}

// ---------------- fused scan: bucket-level exclusive scan (redundant per block)
// + row scan of blockHist -> matrixScan
__global__ __launch_bounds__(256) void scanfused_kernel(
    const int* __restrict__ bucketTotals,
    const int* __restrict__ blockHist,
    int* __restrict__ matrixScan)
{
    __shared__ int bs[256];
    __shared__ int s[256];
    const int t = threadIdx.x, b = blockIdx.x;

    bs[t] = (t < NBUCK) ? bucketTotals[t] : 0;
    __syncthreads();
    #pragma unroll
    for (int off = 1; off < 256; off <<= 1) {
        int u = (t >= off) ? bs[t - off] : 0;
        __syncthreads();
        bs[t] += u;
        __syncthreads();
    }
    const int base = (b == 0) ? 0 : bs[b - 1];

    int c = blockHist[b * 256 + t];
    s[t] = c;
    __syncthreads();
    #pragma unroll
    for (int off = 1; off < 256; off <<= 1) {
        int u = (t >= off) ? s[t - off] : 0;
        __syncthreads();
        s[t] += u;
        __syncthreads();
    }
    matrixScan[b * 256 + t] = base + s[t] - c;   // exclusive prefix
}

// ---------------- binpass: deterministic multi-split, per-(block,bucket) private ranges
__global__ __launch_bounds__(256) void binpass_kernel(
    const int* __restrict__ ei,
    const float* __restrict__ es,
    const float* __restrict__ ed,
    const int* __restrict__ matrixScan,
    int2* __restrict__ binned)
{
    __shared__ int lcur[NBUCK];
    const int t = threadIdx.x, blk = blockIdx.x;
    if (t < NBUCK) lcur[t] = matrixScan[t * 256 + blk];
    __syncthreads();
    const int base = blk * EPB;
    #pragma unroll 1
    for (int it = 0; it < BINIT; ++it) {
        int e = base + it * 256 + t;
        if (e < base + EPB) {
            int s = ei[e];
            int d = ei[N_EDGES + e];
            float a  = es[s] + ed[d];
            float sg = 1.f / (1.f + __expf(-a));
            float w  = __expf(sg);
            int pos = atomicAdd(&lcur[d >> 8], 1);
            binned[pos] = make_int2(s | ((d & 255) << 16), __float_as_int(w));
        }
    }
}

// ---------------- sortpass: one block per bucket; hist over dlow, scan, place.
__global__ __launch_bounds__(256) void sortpass_kernel(
    const int2* __restrict__ binned,
    const int* __restrict__ matrixScan,
    int2* __restrict__ sortedSW,
    int* __restrict__ offset,
    int* __restrict__ count)
{
    __shared__ int lhist[256], lscan[256], lcur[256];
    const int t = threadIdx.x, b = blockIdx.x;
    const int start = matrixScan[b * 256];
    const int end   = (b == NBUCK - 1) ? N_EDGES : matrixScan[(b + 1) * 256];
    const int cnt   = end - start;

    lhist[t] = 0;
    __syncthreads();
    for (int i = t; i < cnt; i += 256)
        atomicAdd(&lhist[(binned[start + i].x >> 16) & 255], 1);
    __syncthreads();

    int v = lhist[t];
    lscan[t] = v;
    __syncthreads();
    #pragma unroll
    for (int off = 1; off < 256; off <<= 1) {
        int u = (t >= off) ? lscan[t - off] : 0;
        __syncthreads();
        lscan[t] += u;
        __syncthreads();
    }
    int excl = lscan[t] - v;

    int node = (b << 8) + t;
    if (node < N_NODES) { offset[node] = start + excl; count[node] = v; }
    lcur[t] = excl;
    __syncthreads();

    for (int i = t; i < cnt; i += 256) {
        int2 ent = binned[start + i];
        int dlow = (ent.x >> 16) & 255;
        int pos = atomicAdd(&lcur[dlow], 1);
        sortedSW[start + pos] = make_int2(ent.x & 0xFFFF, ent.y);
    }
}

// ---------------- gather-aggregate: one wave/node; tiers 16/8/4/1 of MLP;
// fused epilogue: h1b = bf16(elu(acc/wsum)).
__global__ __launch_bounds__(256) void agg_kernel(
    const int2* __restrict__ sortedSW,
    const int* __restrict__ offset,
    const int* __restrict__ count,
    const unsigned short* __restrict__ hb,
    unsigned int* __restrict__ h1b)   // viewed as packed 2x bf16
{
    int node = (blockIdx.x * 256 + threadIdx.x) >> 6;
    int lane = threadIdx.x & 63;
    if (node >= N_NODES) return;

    int beg = offset[node];
    int deg = count[node];

    float2 acc = make_float2(0.f, 0.f);
    float wsum = 0.f;

    for (int base = 0; base < deg; base += 64) {
        int cnt = min(64, deg - base);
        int2 sw = (lane < cnt) ? sortedSW[beg + base + lane] : make_int2(0, 0);
        int j = 0;

#define TIER(T)                                                                 \
        for (; j + T <= cnt; j += T) {                                          \
            unsigned uu[T]; float ww[T];                                        \
            _Pragma("unroll")                                                   \
            for (int k = 0; k < T; ++k) {                                       \
                int s_ = __builtin_amdgcn_readlane(sw.x, j + k);                \
                uu[k] = *(const unsigned*)(hb + (size_t)s_ * DHID + 2 * lane);  \
            }                                                                   \
            _Pragma("unroll")                                                   \
            for (int k = 0; k < T; ++k)                                         \
                ww[k] = __uint_as_float(                                        \
                    (unsigned)__builtin_amdgcn_readlane(sw.y, j + k));          \
            _Pragma("unroll")                                                   \
            for (int k = 0; k < T; ++k) {                                       \
                wsum  += ww[k];                                                 \
                acc.x += ww[k] * __uint_as_float(uu[k] << 16);                  \
                acc.y += ww[k] * __uint_as_float(uu[k] & 0xffff0000u);          \
            }                                                                   \
        }

        TIER(16)
        TIER(8)
        TIER(4)
#undef TIER
        for (; j < cnt; ++j) {
            int   sj = __builtin_amdgcn_readlane(sw.x, j);
            float wj = __uint_as_float((unsigned)__builtin_amdgcn_readlane(sw.y, j));
            unsigned u = *(const unsigned*)(hb + (size_t)sj * DHID + 2 * lane);
            acc.x += wj * __uint_as_float(u << 16);
            acc.y += wj * __uint_as_float(u & 0xffff0000u);
            wsum  += wj;
        }
    }
    float inv = (deg > 0) ? 1.f / wsum : 0.f;
    float v0 = acc.x * inv, v1 = acc.y * inv;
    float e0 = v0 > 0.f ? v0 : (__expf(v0) - 1.f);
    float e1 = v1 > 0.f ? v1 : (__expf(v1) - 1.f);
    h1b[(size_t)node * (DHID / 2) + lane] =
        (unsigned)f2b(e0) | ((unsigned)f2b(e1) << 16);
}

// ---------------- gemm2: out(f32) = h1b @ W2t^T, MFMA, K=128 (pure bf16 A).
__global__ __launch_bounds__(256) void gemm2_mfma(
    const unsigned short* __restrict__ h1b,
    const unsigned short* __restrict__ W2t,
    float* __restrict__ out)
{
    __shared__ unsigned short W2s[DOUT * DHID];   // 32 KB

    const int tid = threadIdx.x;
    const int wave = tid >> 6, lane = tid & 63;
    const int row0 = blockIdx.x * 64 + wave * 16;
    const int m = lane & 15, q = lane >> 4;

    {
        const float4* src = (const float4*)W2t;
        float4* dst = (float4*)W2s;
        #pragma unroll
        for (int i = 0; i < 8; ++i)
            dst[tid + i * 256] = src[tid + i * 256];
    }
    __syncthreads();

    int r  = row0 + m;
    int rc = (r < N_NODES) ? r : 0;

    f32x4 acc[8];
    #pragma unroll
    for (int t = 0; t < 8; ++t) acc[t] = (f32x4){0.f, 0.f, 0.f, 0.f};

    const short* xp = (const short*)h1b + (size_t)rc * DHID + q * 8;
    const short* wp = (const short*)W2s + q * 8;

    #pragma unroll
    for (int kt = 0; kt < 4; ++kt) {
        bf16x8 a = *(const bf16x8*)(xp + kt * 32);
        #pragma unroll
        for (int t = 0; t < 8; ++t) {
            bf16x8 b = *(const bf16x8*)(wp + (t * 16 + m) * DHID + kt * 32);
            acc[t] = __builtin_amdgcn_mfma_f32_16x16x32_bf16(a, b, acc[t], 0, 0, 0);
        }
    }

    #pragma unroll
    for (int reg = 0; reg < 4; ++reg) {
        int rr = row0 + q * 4 + reg;
        if (rr < N_NODES) {
            #pragma unroll
            for (int t = 0; t < 8; ++t)
                out[(size_t)rr * DOUT + t * 16 + m] = acc[t][reg];
        }
    }
}

extern "C" void kernel_launch(void* const* d_in, const int* in_sizes, int n_in,
                              void* d_out, int out_size, void* d_ws, size_t ws_size,
                              hipStream_t stream)
{
    const float* x    = (const float*)d_in[0];
    const int*   ei   = (const int*)d_in[1];
    const float* W1   = (const float*)d_in[2];
    const float* asrc = (const float*)d_in[3];
    const float* adst = (const float*)d_in[4];
    const float* W2   = (const float*)d_in[5];
    float*       out  = (float*)d_out;

    // ---- workspace layout (~40 MB) ----
    char* p = (char*)d_ws;
    unsigned short* hb  = (unsigned short*)p;  p += (size_t)N_NODES * DHID * 2;  // 12.8 MB
    unsigned int*   h1b = (unsigned int*)p;    p += (size_t)N_NODES * DHID * 2;  // 12.8 MB
    unsigned short* W1t = (unsigned short*)p;  p += (size_t)DHID * DIN * 2;      // 64 KB
    unsigned short* W2t = (unsigned short*)p;  p += (size_t)DOUT * DHID * 2;     // 32 KB
    float* es     = (float*)p;  p += (size_t)N_NODES * 4;
    float* ed     = (float*)p;  p += (size_t)N_NODES * 4;
    int*   offset = (int*)p;    p += (size_t)N_NODES * 4;
    int*   count  = (int*)p;    p += (size_t)N_NODES * 4;
    int*   blockHist    = (int*)p; p += (size_t)NBUCK * 256 * 4;                 // 200 KB
    int*   matrixScan   = (int*)p; p += (size_t)NBUCK * 256 * 4;                 // 200 KB
    int*   bucketTotals = (int*)p; p += 256 * 4;
    int2*  binned   = (int2*)p; p += (size_t)N_EDGES * 8;                        // 6.4 MB
    int2*  sortedSW = (int2*)p; p += (size_t)N_EDGES * 8;                        // 6.4 MB

    hipMemsetAsync(bucketTotals, 0, NBUCK * sizeof(int), stream);

    convW_kernel<<<(DIN * DHID + DHID * DOUT) / 256, 256, 0, stream>>>(W1, W2, W1t, W2t);

    gemm1_mfma<<<(N_NODES + 63) / 64, 256, 0, stream>>>(x, W1t, asrc, adst, hb, es, ed);

    lhist_kernel    <<<BINBLK, 256, 0, stream>>>(ei, blockHist, bucketTotals);
    scanfused_kernel<<<NBUCK, 256, 0, stream>>>(bucketTotals, blockHist, matrixScan);
    binpass_kernel  <<<BINBLK, 256, 0, stream>>>(ei, es, ed, matrixScan, binned);
    sortpass_kernel <<<NBUCK, 256, 0, stream>>>(binned, matrixScan, sortedSW, offset, count);

    agg_kernel<<<(N_NODES * 64 + 255) / 256, 256, 0, stream>>>(
        sortedSW, offset, count, hb, h1b);

    gemm2_mfma<<<(N_NODES + 63) / 64, 256, 0, stream>>>((const unsigned short*)h1b, W2t, out);
}